// Round 2
// baseline (1140.696 us; speedup 1.0000x reference)
//
#include <hip/hip_runtime.h>
#include <hip/hip_bf16.h>

// GCN: 2x GraphConv(norm='both') + per-graph mean + [hg|perm] @ Wc + bc
// N=100000, E=1600000, D=H=128, P=64, C=10, G=128

#define BUCKET_CAP 64
#define OVF_CAP 4096

// ---- build per-dst edge buckets + out-degree histogram ----
__global__ void build_kernel(const int* __restrict__ src, const int* __restrict__ dst, int E,
                             int* __restrict__ indeg, int* __restrict__ outdeg,
                             int* __restrict__ bucket, int* __restrict__ ovfc,
                             int* __restrict__ ovfl) {
    int e = blockIdx.x * blockDim.x + threadIdx.x;
    if (e >= E) return;
    int s = src[e], d = dst[e];
    atomicAdd(&outdeg[s], 1);
    int slot = atomicAdd(&indeg[d], 1);
    if (slot < BUCKET_CAP) {
        bucket[(size_t)d * BUCKET_CAP + slot] = s;
    } else {
        int p = atomicAdd(ovfc, 1);
        if (p < OVF_CAP) ovfl[p] = e;
    }
}

// ---- per-graph node-count histogram ----
__global__ void hist_kernel(const int* __restrict__ gids, int N, int* __restrict__ counts) {
    int i = blockIdx.x * blockDim.x + threadIdx.x;
    if (i >= N) return;
    atomicAdd(&counts[gids[i]], 1);
}

// ---- degree -> rsqrt norms ----
__global__ void norm_kernel(const int* __restrict__ outdeg, const int* __restrict__ indeg,
                            float* __restrict__ nrm_out, float* __restrict__ nrm_in, int N) {
    int i = blockIdx.x * blockDim.x + threadIdx.x;
    if (i >= N) return;
    nrm_out[i] = rsqrtf(fmaxf((float)outdeg[i], 1.0f));
    nrm_in[i]  = rsqrtf(fmaxf((float)indeg[i], 1.0f));
}

// ---- serial exclusive scan over 128 graph counts ----
__global__ void scan_kernel(const int* __restrict__ counts, int* __restrict__ goffs, int G) {
    if (blockIdx.x == 0 && threadIdx.x == 0) {
        int acc = 0;
        for (int g = 0; g < G; g++) { goffs[g] = acc; acc += counts[g]; }
        goffs[G] = acc;
    }
}

// ---- aggregation: one 32-lane group per node, float4 per lane, no atomics ----
__global__ void agg_kernel(const float* __restrict__ x, const float* __restrict__ nrm_out,
                           const int* __restrict__ bucket, const int* __restrict__ indeg,
                           float* __restrict__ agg, int N) {
    int t = blockIdx.x * blockDim.x + threadIdx.x;
    int node = t >> 5;
    int q = t & 31;
    if (node >= N) return;
    int deg = indeg[node];
    if (deg > BUCKET_CAP) deg = BUCKET_CAP;
    const int* bk = bucket + (size_t)node * BUCKET_CAP;
    float4 acc = make_float4(0.f, 0.f, 0.f, 0.f);
    for (int j = 0; j < deg; j++) {
        int s = bk[j];
        float ns = nrm_out[s];
        float4 v = ((const float4*)x)[(size_t)s * 32 + q];
        acc.x += ns * v.x; acc.y += ns * v.y; acc.z += ns * v.z; acc.w += ns * v.w;
    }
    ((float4*)agg)[(size_t)node * 32 + q] = acc;
}

// ---- rare bucket-overflow edges: atomic fallback (expected count: 0) ----
__global__ void ovf_kernel(const float* __restrict__ x, const float* __restrict__ nrm_out,
                           const int* __restrict__ src, const int* __restrict__ dst,
                           const int* __restrict__ ovfc, const int* __restrict__ ovfl,
                           float* __restrict__ agg) {
    int t = blockIdx.x * blockDim.x + threadIdx.x;
    int idx = t >> 5, q = t & 31;
    int n = *ovfc;
    if (n > OVF_CAP) n = OVF_CAP;
    if (idx >= n) return;
    int e = ovfl[idx];
    int s = src[e], d = dst[e];
    float ns = nrm_out[s];
    float4 v = ((const float4*)x)[(size_t)s * 32 + q];
    float* ap = agg + (size_t)d * 128 + q * 4;
    atomicAdd(ap + 0, ns * v.x);
    atomicAdd(ap + 1, ns * v.y);
    atomicAdd(ap + 2, ns * v.z);
    atomicAdd(ap + 3, ns * v.w);
}

// ---- out[r][c] = act(rowscale[r] * sum_k A[r][k]*W[k][c] + bias[c]) ----
// W (128x128) fully in LDS (64 KB). 256 threads: 64 row-pairs x 4 col-groups.
// Column ownership interleaved (c = m*16 + gi*4): the 4 gi-threads of a row
// read distinct bank quads -> conflict-free ds_read_b128.
__global__ __launch_bounds__(256) void gemm128(const float* __restrict__ A,
                                               const float* __restrict__ W,
                                               const float* __restrict__ bias,
                                               const float* __restrict__ rowscale,
                                               float* __restrict__ out, int N, int do_relu) {
    __shared__ float Wl[128 * 128];
    for (int i = threadIdx.x; i < 4096; i += 256)
        ((float4*)Wl)[i] = ((const float4*)W)[i];
    __syncthreads();

    int gi = threadIdx.x & 3;
    int rp = threadIdx.x >> 2;
    int r0 = blockIdx.x * 128 + rp * 2;
    if (r0 >= N) return;
    bool two = (r0 + 1 < N);

    const float* A0 = A + (size_t)r0 * 128;
    const float* A1 = two ? (A0 + 128) : A0;

    float acc0[32], acc1[32];
#pragma unroll
    for (int j = 0; j < 32; j++) { acc0[j] = 0.f; acc1[j] = 0.f; }

    for (int k4 = 0; k4 < 32; k4++) {
        float4 a0 = ((const float4*)A0)[k4];
        float4 a1 = ((const float4*)A1)[k4];
#pragma unroll
        for (int kk = 0; kk < 4; kk++) {
            int k = k4 * 4 + kk;
            float av0 = (kk == 0) ? a0.x : (kk == 1) ? a0.y : (kk == 2) ? a0.z : a0.w;
            float av1 = (kk == 0) ? a1.x : (kk == 1) ? a1.y : (kk == 2) ? a1.z : a1.w;
            const float* wrow = Wl + k * 128 + gi * 4;
#pragma unroll
            for (int m = 0; m < 8; m++) {
                float4 wv = *(const float4*)(wrow + m * 16);
                acc0[m * 4 + 0] = fmaf(av0, wv.x, acc0[m * 4 + 0]);
                acc0[m * 4 + 1] = fmaf(av0, wv.y, acc0[m * 4 + 1]);
                acc0[m * 4 + 2] = fmaf(av0, wv.z, acc0[m * 4 + 2]);
                acc0[m * 4 + 3] = fmaf(av0, wv.w, acc0[m * 4 + 3]);
                acc1[m * 4 + 0] = fmaf(av1, wv.x, acc1[m * 4 + 0]);
                acc1[m * 4 + 1] = fmaf(av1, wv.y, acc1[m * 4 + 1]);
                acc1[m * 4 + 2] = fmaf(av1, wv.z, acc1[m * 4 + 2]);
                acc1[m * 4 + 3] = fmaf(av1, wv.w, acc1[m * 4 + 3]);
            }
        }
    }

    float s0 = rowscale[r0];
    float s1 = two ? rowscale[r0 + 1] : 0.f;
    float* o0 = out + (size_t)r0 * 128;
#pragma unroll
    for (int m = 0; m < 8; m++) {
        int c = m * 16 + gi * 4;
        float4 b4 = *(const float4*)(bias + c);
        float4 v0, v1;
        v0.x = fmaf(s0, acc0[m * 4 + 0], b4.x);
        v0.y = fmaf(s0, acc0[m * 4 + 1], b4.y);
        v0.z = fmaf(s0, acc0[m * 4 + 2], b4.z);
        v0.w = fmaf(s0, acc0[m * 4 + 3], b4.w);
        if (do_relu) {
            v0.x = fmaxf(v0.x, 0.f); v0.y = fmaxf(v0.y, 0.f);
            v0.z = fmaxf(v0.z, 0.f); v0.w = fmaxf(v0.w, 0.f);
        }
        *(float4*)(o0 + c) = v0;
        if (two) {
            v1.x = fmaf(s1, acc1[m * 4 + 0], b4.x);
            v1.y = fmaf(s1, acc1[m * 4 + 1], b4.y);
            v1.z = fmaf(s1, acc1[m * 4 + 2], b4.z);
            v1.w = fmaf(s1, acc1[m * 4 + 3], b4.w);
            if (do_relu) {
                v1.x = fmaxf(v1.x, 0.f); v1.y = fmaxf(v1.y, 0.f);
                v1.z = fmaxf(v1.z, 0.f); v1.w = fmaxf(v1.w, 0.f);
            }
            *(float4*)(o0 + 128 + c) = v1;
        }
    }
}

// ---- per-graph mean (graph_ids sorted -> contiguous row ranges) ----
__global__ void mean_kernel(const float* __restrict__ x2, const int* __restrict__ goffs,
                            float* __restrict__ hg) {
    int g = blockIdx.x;
    int c = threadIdx.x;  // 128
    int s = goffs[g], e = goffs[g + 1];
    float acc = 0.f;
    for (int r = s; r < e; r++) acc += x2[(size_t)r * 128 + c];
    float cnt = fmaxf((float)(e - s), 1.0f);
    hg[g * 128 + c] = acc / cnt;
}

// ---- classifier head: [G,128|64] @ Wc[192,10] + bc ----
__global__ void final_kernel(const float* __restrict__ hg, const float* __restrict__ perm,
                             const float* __restrict__ Wc, const float* __restrict__ bc,
                             float* __restrict__ out, int G) {
    int t = blockIdx.x * blockDim.x + threadIdx.x;
    if (t >= G * 10) return;
    int g = t / 10, c = t % 10;
    float acc = bc[c];
    const float* hrow = hg + g * 128;
#pragma unroll 8
    for (int k = 0; k < 128; k++) acc = fmaf(hrow[k], Wc[k * 10 + c], acc);
    const float* prow = perm + g * 64;
#pragma unroll 8
    for (int p = 0; p < 64; p++) acc = fmaf(prow[p], Wc[(128 + p) * 10 + c], acc);
    out[t] = acc;
}

extern "C" void kernel_launch(void* const* d_in, const int* in_sizes, int n_in,
                              void* d_out, int out_size, void* d_ws, size_t ws_size,
                              hipStream_t stream) {
    const float* h    = (const float*)d_in[0];
    const float* perm = (const float*)d_in[1];
    const float* W1   = (const float*)d_in[2];
    const float* b1   = (const float*)d_in[3];
    const float* W2   = (const float*)d_in[4];
    const float* b2   = (const float*)d_in[5];
    const float* Wc   = (const float*)d_in[6];
    const float* bc   = (const float*)d_in[7];
    const int* src    = (const int*)d_in[8];
    const int* dst    = (const int*)d_in[9];
    const int* gids   = (const int*)d_in[10];
    float* out = (float*)d_out;

    const int N = in_sizes[0] / 128;
    const int E = in_sizes[8];
    const int G = 128, H = 128;

    char* w = (char*)d_ws;
    size_t off = 0;
    auto alloc = [&](size_t bytes) -> void* {
        void* p = w + off;
        off = (off + bytes + 255) & ~(size_t)255;
        return p;
    };
    float* agg      = (float*)alloc((size_t)N * H * 4);
    float* x1       = (float*)alloc((size_t)N * H * 4);
    int*   bucket   = (int*)alloc((size_t)N * BUCKET_CAP * 4);
    int*   indeg    = (int*)alloc((size_t)N * 4);
    int*   outdeg   = (int*)alloc((size_t)N * 4);
    float* nrm_out  = (float*)alloc((size_t)N * 4);
    float* nrm_in   = (float*)alloc((size_t)N * 4);
    int*   counts   = (int*)alloc((size_t)G * 4);
    int*   goffs    = (int*)alloc((size_t)(G + 1) * 4);
    float* hg       = (float*)alloc((size_t)G * H * 4);
    int*   ovfc     = (int*)alloc(256);
    int*   ovfl     = (int*)alloc((size_t)OVF_CAP * 4);

    (void)hipMemsetAsync(indeg, 0, (size_t)N * 4, stream);
    (void)hipMemsetAsync(outdeg, 0, (size_t)N * 4, stream);
    (void)hipMemsetAsync(counts, 0, (size_t)G * 4, stream);
    (void)hipMemsetAsync(ovfc, 0, 4, stream);

    build_kernel<<<(E + 255) / 256, 256, 0, stream>>>(src, dst, E, indeg, outdeg, bucket, ovfc, ovfl);
    hist_kernel<<<(N + 255) / 256, 256, 0, stream>>>(gids, N, counts);
    norm_kernel<<<(N + 255) / 256, 256, 0, stream>>>(outdeg, indeg, nrm_out, nrm_in, N);
    scan_kernel<<<1, 64, 0, stream>>>(counts, goffs, G);

    // layer 1
    agg_kernel<<<(N * 32 + 255) / 256, 256, 0, stream>>>(h, nrm_out, bucket, indeg, agg, N);
    ovf_kernel<<<(OVF_CAP * 32) / 256, 256, 0, stream>>>(h, nrm_out, src, dst, ovfc, ovfl, agg);
    gemm128<<<(N + 127) / 128, 256, 0, stream>>>(agg, W1, b1, nrm_in, x1, N, 1);

    // layer 2
    agg_kernel<<<(N * 32 + 255) / 256, 256, 0, stream>>>(x1, nrm_out, bucket, indeg, agg, N);
    ovf_kernel<<<(OVF_CAP * 32) / 256, 256, 0, stream>>>(x1, nrm_out, src, dst, ovfc, ovfl, agg);
    gemm128<<<(N + 127) / 128, 256, 0, stream>>>(agg, W2, b2, nrm_in, x1, N, 0);

    // readout
    mean_kernel<<<G, 128, 0, stream>>>(x1, goffs, hg);
    final_kernel<<<(G * 10 + 255) / 256, 256, 0, stream>>>(hg, perm, Wc, bc, out, G);
}

// Round 3
// 687.151 us; speedup vs baseline: 1.6600x; 1.6600x over previous
//
#include <hip/hip_runtime.h>
#include <hip/hip_bf16.h>

// GCN: 2x GraphConv(norm='both') + per-graph mean + [hg|perm] @ Wc + bc
// N=100000, E=1600000, D=H=128, P=64, C=10, G=128

#define BUCKET_CAP 64
#define OVF_CAP 4096
#define NUM_G 128

// ---- build per-dst edge buckets + out-degree histogram ----
__global__ void build_kernel(const int* __restrict__ src, const int* __restrict__ dst, int E,
                             int* __restrict__ indeg, int* __restrict__ outdeg,
                             int* __restrict__ bucket, int* __restrict__ ovfc,
                             int* __restrict__ ovfl) {
    int e = blockIdx.x * blockDim.x + threadIdx.x;
    if (e >= E) return;
    int s = src[e], d = dst[e];
    atomicAdd(&outdeg[s], 1);
    int slot = atomicAdd(&indeg[d], 1);
    if (slot < BUCKET_CAP) {
        bucket[(size_t)d * BUCKET_CAP + slot] = s;
    } else {
        int p = atomicAdd(ovfc, 1);
        if (p < OVF_CAP) ovfl[p] = e;
    }
}

// ---- graph_ids sorted -> segment offsets by boundary detection (NO atomics) ----
// goffs[g] = first node index i with gids[i] >= g;  goffs[G] = N.
__global__ void goffs_kernel(const int* __restrict__ gids, int N, int* __restrict__ goffs) {
    int i = blockIdx.x * blockDim.x + threadIdx.x;
    if (i > N) return;
    int prev = (i == 0) ? -1 : gids[i - 1];
    int cur  = (i == N) ? NUM_G : gids[i];
    for (int g = prev + 1; g <= cur && g <= NUM_G; g++) goffs[g] = i;
}

// ---- degree -> rsqrt norms ----
__global__ void norm_kernel(const int* __restrict__ outdeg, const int* __restrict__ indeg,
                            float* __restrict__ nrm_out, float* __restrict__ nrm_in, int N) {
    int i = blockIdx.x * blockDim.x + threadIdx.x;
    if (i >= N) return;
    nrm_out[i] = rsqrtf(fmaxf((float)outdeg[i], 1.0f));
    nrm_in[i]  = rsqrtf(fmaxf((float)indeg[i], 1.0f));
}

// ---- aggregation: one 32-lane group per node, float4 per lane, no atomics ----
__global__ void agg_kernel(const float* __restrict__ x, const float* __restrict__ nrm_out,
                           const int* __restrict__ bucket, const int* __restrict__ indeg,
                           float* __restrict__ agg, int N) {
    int t = blockIdx.x * blockDim.x + threadIdx.x;
    int node = t >> 5;
    int q = t & 31;
    if (node >= N) return;
    int deg = indeg[node];
    if (deg > BUCKET_CAP) deg = BUCKET_CAP;
    const int* bk = bucket + (size_t)node * BUCKET_CAP;
    float4 acc = make_float4(0.f, 0.f, 0.f, 0.f);
    for (int j = 0; j < deg; j++) {
        int s = bk[j];
        float ns = nrm_out[s];
        float4 v = ((const float4*)x)[(size_t)s * 32 + q];
        acc.x += ns * v.x; acc.y += ns * v.y; acc.z += ns * v.z; acc.w += ns * v.w;
    }
    ((float4*)agg)[(size_t)node * 32 + q] = acc;
}

// ---- rare bucket-overflow edges: atomic fallback (expected count: 0) ----
__global__ void ovf_kernel(const float* __restrict__ x, const float* __restrict__ nrm_out,
                           const int* __restrict__ src, const int* __restrict__ dst,
                           const int* __restrict__ ovfc, const int* __restrict__ ovfl,
                           float* __restrict__ agg) {
    int t = blockIdx.x * blockDim.x + threadIdx.x;
    int idx = t >> 5, q = t & 31;
    int n = *ovfc;
    if (n > OVF_CAP) n = OVF_CAP;
    if (idx >= n) return;
    int e = ovfl[idx];
    int s = src[e], d = dst[e];
    float ns = nrm_out[s];
    float4 v = ((const float4*)x)[(size_t)s * 32 + q];
    float* ap = agg + (size_t)d * 128 + q * 4;
    atomicAdd(ap + 0, ns * v.x);
    atomicAdd(ap + 1, ns * v.y);
    atomicAdd(ap + 2, ns * v.z);
    atomicAdd(ap + 3, ns * v.w);
}

// ---- out[r][c] = act(rowscale[r] * sum_k A[r][k]*W[k][c] + bias[c]) ----
// W (128x128) fully in LDS (64 KB). 256 threads: 64 row-pairs x 4 col-groups.
__global__ __launch_bounds__(256) void gemm128(const float* __restrict__ A,
                                               const float* __restrict__ W,
                                               const float* __restrict__ bias,
                                               const float* __restrict__ rowscale,
                                               float* __restrict__ out, int N, int do_relu) {
    __shared__ float Wl[128 * 128];
    for (int i = threadIdx.x; i < 4096; i += 256)
        ((float4*)Wl)[i] = ((const float4*)W)[i];
    __syncthreads();

    int gi = threadIdx.x & 3;
    int rp = threadIdx.x >> 2;
    int r0 = blockIdx.x * 128 + rp * 2;
    if (r0 >= N) return;
    bool two = (r0 + 1 < N);

    const float* A0 = A + (size_t)r0 * 128;
    const float* A1 = two ? (A0 + 128) : A0;

    float acc0[32], acc1[32];
#pragma unroll
    for (int j = 0; j < 32; j++) { acc0[j] = 0.f; acc1[j] = 0.f; }

    for (int k4 = 0; k4 < 32; k4++) {
        float4 a0 = ((const float4*)A0)[k4];
        float4 a1 = ((const float4*)A1)[k4];
#pragma unroll
        for (int kk = 0; kk < 4; kk++) {
            int k = k4 * 4 + kk;
            float av0 = (kk == 0) ? a0.x : (kk == 1) ? a0.y : (kk == 2) ? a0.z : a0.w;
            float av1 = (kk == 0) ? a1.x : (kk == 1) ? a1.y : (kk == 2) ? a1.z : a1.w;
            const float* wrow = Wl + k * 128 + gi * 4;
#pragma unroll
            for (int m = 0; m < 8; m++) {
                float4 wv = *(const float4*)(wrow + m * 16);
                acc0[m * 4 + 0] = fmaf(av0, wv.x, acc0[m * 4 + 0]);
                acc0[m * 4 + 1] = fmaf(av0, wv.y, acc0[m * 4 + 1]);
                acc0[m * 4 + 2] = fmaf(av0, wv.z, acc0[m * 4 + 2]);
                acc0[m * 4 + 3] = fmaf(av0, wv.w, acc0[m * 4 + 3]);
                acc1[m * 4 + 0] = fmaf(av1, wv.x, acc1[m * 4 + 0]);
                acc1[m * 4 + 1] = fmaf(av1, wv.y, acc1[m * 4 + 1]);
                acc1[m * 4 + 2] = fmaf(av1, wv.z, acc1[m * 4 + 2]);
                acc1[m * 4 + 3] = fmaf(av1, wv.w, acc1[m * 4 + 3]);
            }
        }
    }

    float s0 = rowscale[r0];
    float s1 = two ? rowscale[r0 + 1] : 0.f;
    float* o0 = out + (size_t)r0 * 128;
#pragma unroll
    for (int m = 0; m < 8; m++) {
        int c = m * 16 + gi * 4;
        float4 b4 = *(const float4*)(bias + c);
        float4 v0, v1;
        v0.x = fmaf(s0, acc0[m * 4 + 0], b4.x);
        v0.y = fmaf(s0, acc0[m * 4 + 1], b4.y);
        v0.z = fmaf(s0, acc0[m * 4 + 2], b4.z);
        v0.w = fmaf(s0, acc0[m * 4 + 3], b4.w);
        if (do_relu) {
            v0.x = fmaxf(v0.x, 0.f); v0.y = fmaxf(v0.y, 0.f);
            v0.z = fmaxf(v0.z, 0.f); v0.w = fmaxf(v0.w, 0.f);
        }
        *(float4*)(o0 + c) = v0;
        if (two) {
            v1.x = fmaf(s1, acc1[m * 4 + 0], b4.x);
            v1.y = fmaf(s1, acc1[m * 4 + 1], b4.y);
            v1.z = fmaf(s1, acc1[m * 4 + 2], b4.z);
            v1.w = fmaf(s1, acc1[m * 4 + 3], b4.w);
            if (do_relu) {
                v1.x = fmaxf(v1.x, 0.f); v1.y = fmaxf(v1.y, 0.f);
                v1.z = fmaxf(v1.z, 0.f); v1.w = fmaxf(v1.w, 0.f);
            }
            *(float4*)(o0 + 128 + c) = v1;
        }
    }
}

// ---- per-graph mean: block per graph, 8 row-lanes x 128 cols + LDS reduce ----
__global__ __launch_bounds__(1024) void mean_kernel(const float* __restrict__ x2,
                                                    const int* __restrict__ goffs,
                                                    float* __restrict__ hg) {
    __shared__ float red[8][128];
    int g = blockIdx.x;
    int c = threadIdx.x & 127;
    int j = threadIdx.x >> 7;  // 0..7
    int s = goffs[g], e = goffs[g + 1];
    float acc = 0.f;
    for (int r = s + j; r < e; r += 8) acc += x2[(size_t)r * 128 + c];
    red[j][c] = acc;
    __syncthreads();
    if (j == 0) {
        float t = red[0][c];
#pragma unroll
        for (int jj = 1; jj < 8; jj++) t += red[jj][c];
        float cnt = fmaxf((float)(e - s), 1.0f);
        hg[g * 128 + c] = t / cnt;
    }
}

// ---- classifier head: [G,128|64] @ Wc[192,10] + bc ----
__global__ void final_kernel(const float* __restrict__ hg, const float* __restrict__ perm,
                             const float* __restrict__ Wc, const float* __restrict__ bc,
                             float* __restrict__ out, int G) {
    int t = blockIdx.x * blockDim.x + threadIdx.x;
    if (t >= G * 10) return;
    int g = t / 10, c = t % 10;
    float acc = bc[c];
    const float* hrow = hg + g * 128;
#pragma unroll 8
    for (int k = 0; k < 128; k++) acc = fmaf(hrow[k], Wc[k * 10 + c], acc);
    const float* prow = perm + g * 64;
#pragma unroll 8
    for (int p = 0; p < 64; p++) acc = fmaf(prow[p], Wc[(128 + p) * 10 + c], acc);
    out[t] = acc;
}

extern "C" void kernel_launch(void* const* d_in, const int* in_sizes, int n_in,
                              void* d_out, int out_size, void* d_ws, size_t ws_size,
                              hipStream_t stream) {
    const float* h    = (const float*)d_in[0];
    const float* perm = (const float*)d_in[1];
    const float* W1   = (const float*)d_in[2];
    const float* b1   = (const float*)d_in[3];
    const float* W2   = (const float*)d_in[4];
    const float* b2   = (const float*)d_in[5];
    const float* Wc   = (const float*)d_in[6];
    const float* bc   = (const float*)d_in[7];
    const int* src    = (const int*)d_in[8];
    const int* dst    = (const int*)d_in[9];
    const int* gids   = (const int*)d_in[10];
    float* out = (float*)d_out;

    const int N = in_sizes[0] / 128;
    const int E = in_sizes[8];
    const int G = NUM_G, H = 128;

    char* w = (char*)d_ws;
    size_t off = 0;
    auto alloc = [&](size_t bytes) -> void* {
        void* p = w + off;
        off = (off + bytes + 255) & ~(size_t)255;
        return p;
    };
    float* agg      = (float*)alloc((size_t)N * H * 4);
    float* x1       = (float*)alloc((size_t)N * H * 4);
    int*   bucket   = (int*)alloc((size_t)N * BUCKET_CAP * 4);
    int*   indeg    = (int*)alloc((size_t)N * 4);
    int*   outdeg   = (int*)alloc((size_t)N * 4);
    float* nrm_out  = (float*)alloc((size_t)N * 4);
    float* nrm_in   = (float*)alloc((size_t)N * 4);
    int*   goffs    = (int*)alloc((size_t)(G + 1) * 4);
    float* hg       = (float*)alloc((size_t)G * H * 4);
    int*   ovfc     = (int*)alloc(256);
    int*   ovfl     = (int*)alloc((size_t)OVF_CAP * 4);

    (void)hipMemsetAsync(indeg, 0, (size_t)N * 4, stream);
    (void)hipMemsetAsync(outdeg, 0, (size_t)N * 4, stream);
    (void)hipMemsetAsync(ovfc, 0, 4, stream);

    build_kernel<<<(E + 255) / 256, 256, 0, stream>>>(src, dst, E, indeg, outdeg, bucket, ovfc, ovfl);
    goffs_kernel<<<(N + 1 + 255) / 256, 256, 0, stream>>>(gids, N, goffs);
    norm_kernel<<<(N + 255) / 256, 256, 0, stream>>>(outdeg, indeg, nrm_out, nrm_in, N);

    // layer 1
    agg_kernel<<<(N * 32 + 255) / 256, 256, 0, stream>>>(h, nrm_out, bucket, indeg, agg, N);
    ovf_kernel<<<(OVF_CAP * 32) / 256, 256, 0, stream>>>(h, nrm_out, src, dst, ovfc, ovfl, agg);
    gemm128<<<(N + 127) / 128, 256, 0, stream>>>(agg, W1, b1, nrm_in, x1, N, 1);

    // layer 2
    agg_kernel<<<(N * 32 + 255) / 256, 256, 0, stream>>>(x1, nrm_out, bucket, indeg, agg, N);
    ovf_kernel<<<(OVF_CAP * 32) / 256, 256, 0, stream>>>(x1, nrm_out, src, dst, ovfc, ovfl, agg);
    gemm128<<<(N + 127) / 128, 256, 0, stream>>>(agg, W2, b2, nrm_in, x1, N, 0);

    // readout
    mean_kernel<<<G, 1024, 0, stream>>>(x1, goffs, hg);
    final_kernel<<<(G * 10 + 255) / 256, 256, 0, stream>>>(hg, perm, Wc, bc, out, G);
}